// Round 3
// baseline (875.252 us; speedup 1.0000x reference)
//
#include <hip/hip_runtime.h>

typedef __attribute__((ext_vector_type(8))) short short8;
typedef __attribute__((ext_vector_type(4))) float floatx4;
typedef unsigned short ushort_t;

// ---------- helpers ----------
__device__ __forceinline__ ushort_t f2bf(float x) {
  union { float f; unsigned int u; } v; v.f = x;
  unsigned int u = v.u;
  return (ushort_t)((u + 0x7FFFu + ((u >> 16) & 1u)) >> 16);  // RNE
}
__device__ __forceinline__ unsigned int pk2(float a, float b) {
  return (unsigned int)f2bf(a) | ((unsigned int)f2bf(b) << 16);
}

// ---------- prep: transpose+convert weights to bf16 ----------
__global__ void prep_kernel(const float* __restrict__ W1, const float* __restrict__ W2,
                            ushort_t* __restrict__ W1T, ushort_t* __restrict__ W2T) {
  int idx = blockIdx.x * 256 + threadIdx.x;   // 0 .. 131071
  if (idx < 256 * 512) {
    int n = idx >> 9, k = idx & 511;          // W1T[n][k] = W1[k][n]
    W1T[idx] = f2bf(W1[k * 256 + n]);
    int n2 = idx >> 8, k2 = idx & 255;        // W2T[n2][k2] = W2[k2][n2]
    W2T[idx] = f2bf(W2[k2 * 512 + n2]);
  }
}

// ---------- fp32 -> bf16 streaming convert (two tensors fused) ----------
__global__ void cvt2_kernel(const float* __restrict__ s1, ushort_t* __restrict__ d1, long n1_8,
                            const float* __restrict__ s2, ushort_t* __restrict__ d2, long n2_8) {
  long i = (long)blockIdx.x * 256 + threadIdx.x;
  const float* s; ushort_t* d; long e;
  if (i < n1_8) { s = s1; d = d1; e = i * 8; }
  else { i -= n1_8; if (i >= n2_8) return; s = s2; d = d2; e = i * 8; }
  float4 a = *(const float4*)(s + e);
  float4 b = *(const float4*)(s + e + 4);
  uint4 o = make_uint4(pk2(a.x, a.y), pk2(a.z, a.w), pk2(b.x, b.y), pk2(b.z, b.w));
  *(uint4*)(d + e) = o;
}

// ---------- GEMM: C[M,N] = A[M,K]*B[K,N], B given as BT[N,K] row-major ----------
// Block tile MT x NT (MT*NT <= 32768), 4 waves 2x2; per-wave MF x NF frags of 16x16.
// BK=32; one-tile register prefetch. fp32 operands (ABF/BBF=false, TILE==128 only)
// converted to bf16 in-register during staging.
// EPI: 0 bf16 store ; 2 relu(C+bias[m]) row-summed -> atomicAdd gacc[m] ;
//      3 fp32 partial at split-K z offset.
template<int MT, int NT, bool ABF, bool BBF, int EPI>
__global__ __launch_bounds__(256, 2)
void gemm_bf(const void* __restrict__ Ap, const void* __restrict__ Bp,
             const float* __restrict__ bias, void* __restrict__ Cv,
             float* __restrict__ gacc, const int K, const int N) {
  static_assert(MT == 128 || MT == 256, "");
  static_assert(NT == 128 || NT == 256, "");
  static_assert(MT * NT <= 128 * 256, "");
  static_assert(ABF || MT == 128, "");
  static_assert(BBF || NT == 128, "");
  constexpr int MF = MT / 32, NF = NT / 32;   // frags per wave
  constexpr int ACH = (MT == 256) ? 4 : 2;    // uint4 chunks per thread (A)
  constexpr int BCH = (NT == 256) ? 4 : 2;

  // LDS quad-major: element (row,k) at [(k>>3)*TILE + row]*8 + (k&7)
  __shared__ ushort_t Als[MT * 32];
  __shared__ ushort_t Bls[NT * 32];

  const int t = threadIdx.x;
  const int lane = t & 63;
  const int w = t >> 6;
  const int wm = w >> 1, wn = w & 1;
  const int ml = lane & 15, quad = lane >> 4;
  const int m0 = blockIdx.y * MT, n0 = blockIdx.x * NT;
  const int Kper = K / gridDim.z;
  const int kbeg = blockIdx.z * Kper;

  const ushort_t* Ab = (const ushort_t*)Ap; const float* Af = (const float*)Ap;
  const ushort_t* Bb = (const ushort_t*)Bp; const float* Bf = (const float*)Bp;

  long aoff = (MT == 256) ? ((long)(m0 + t) * K + kbeg)
                          : ((long)(m0 + (t >> 1)) * K + kbeg + (t & 1) * 16);
  long boff = (NT == 256) ? ((long)(n0 + t) * K + kbeg)
                          : ((long)(n0 + (t >> 1)) * K + kbeg + (t & 1) * 16);

  floatx4 acc[MF][NF] = {};

  uint4 aS[ACH], bS[BCH];
  float4 aF[4], bF[4];

  auto loadA = [&]() {
    if constexpr (ABF) {
#pragma unroll
      for (int c = 0; c < ACH; ++c) aS[c] = *(const uint4*)(Ab + aoff + 8 * c);
    } else {
#pragma unroll
      for (int c = 0; c < 4; ++c) aF[c] = *(const float4*)(Af + aoff + 4 * c);
    }
    aoff += 32;
  };
  auto loadB = [&]() {
    if constexpr (BBF) {
#pragma unroll
      for (int c = 0; c < BCH; ++c) bS[c] = *(const uint4*)(Bb + boff + 8 * c);
    } else {
#pragma unroll
      for (int c = 0; c < 4; ++c) bF[c] = *(const float4*)(Bf + boff + 4 * c);
    }
    boff += 32;
  };
  auto stageA = [&]() {
    uint4 wv[ACH];
    if constexpr (ABF) {
#pragma unroll
      for (int c = 0; c < ACH; ++c) wv[c] = aS[c];
    } else {
      wv[0] = make_uint4(pk2(aF[0].x, aF[0].y), pk2(aF[0].z, aF[0].w),
                         pk2(aF[1].x, aF[1].y), pk2(aF[1].z, aF[1].w));
      wv[1] = make_uint4(pk2(aF[2].x, aF[2].y), pk2(aF[2].z, aF[2].w),
                         pk2(aF[3].x, aF[3].y), pk2(aF[3].z, aF[3].w));
    }
    if constexpr (MT == 256) {
#pragma unroll
      for (int c = 0; c < 4; ++c) *(uint4*)(Als + ((c * 256 + t) * 8)) = wv[c];
    } else {
      const int row = t >> 1, h = t & 1;
      *(uint4*)(Als + (((2 * h) * 128 + row) * 8)) = wv[0];
      *(uint4*)(Als + (((2 * h + 1) * 128 + row) * 8)) = wv[1];
    }
  };
  auto stageB = [&]() {
    uint4 wv[BCH];
    if constexpr (BBF) {
#pragma unroll
      for (int c = 0; c < BCH; ++c) wv[c] = bS[c];
    } else {
      wv[0] = make_uint4(pk2(bF[0].x, bF[0].y), pk2(bF[0].z, bF[0].w),
                         pk2(bF[1].x, bF[1].y), pk2(bF[1].z, bF[1].w));
      wv[1] = make_uint4(pk2(bF[2].x, bF[2].y), pk2(bF[2].z, bF[2].w),
                         pk2(bF[3].x, bF[3].y), pk2(bF[3].z, bF[3].w));
    }
    if constexpr (NT == 256) {
#pragma unroll
      for (int c = 0; c < 4; ++c) *(uint4*)(Bls + ((c * 256 + t) * 8)) = wv[c];
    } else {
      const int row = t >> 1, h = t & 1;
      *(uint4*)(Bls + (((2 * h) * 128 + row) * 8)) = wv[0];
      *(uint4*)(Bls + (((2 * h + 1) * 128 + row) * 8)) = wv[1];
    }
  };

  loadA(); loadB();                 // prologue: tile 0 in flight
  const int iters = Kper >> 5;
  for (int it = 0; it < iters; ++it) {
    __syncthreads();                // prior iter's LDS reads complete
    stageA(); stageB();             // waits on in-flight loads, writes LDS
    if (it + 1 < iters) { loadA(); loadB(); }  // next tile lands during MFMA
    __syncthreads();

    short8 av[MF], bv[NF];
#pragma unroll
    for (int f = 0; f < MF; ++f)
      av[f] = *(const short8*)(Als + (quad * MT + wm * (MT / 2) + f * 16 + ml) * 8);
#pragma unroll
    for (int f = 0; f < NF; ++f)
      bv[f] = *(const short8*)(Bls + (quad * NT + wn * (NT / 2) + f * 16 + ml) * 8);
#pragma unroll
    for (int fm = 0; fm < MF; ++fm)
#pragma unroll
      for (int fn = 0; fn < NF; ++fn)
        acc[fm][fn] = __builtin_amdgcn_mfma_f32_16x16x32_bf16(av[fm], bv[fn], acc[fm][fn], 0, 0, 0);
  }

  // ---------------- epilogue ----------------
  if constexpr (EPI == 2) {
#pragma unroll
    for (int fm = 0; fm < MF; ++fm) {
      int rowb = m0 + wm * (MT / 2) + fm * 16 + quad * 4;
#pragma unroll
      for (int r = 0; r < 4; ++r) {
        float bb = bias[rowb + r];
        float s = 0.f;
#pragma unroll
        for (int fn = 0; fn < NF; ++fn)
          s += fmaxf(acc[fm][fn][r] + bb, 0.f);
        s += __shfl_xor(s, 1);
        s += __shfl_xor(s, 2);
        s += __shfl_xor(s, 4);
        s += __shfl_xor(s, 8);
        if (ml == 0) atomicAdd(gacc + rowb + r, s);
      }
    }
  } else if constexpr (EPI == 3) {
    float* Cf = (float*)Cv;
    const long zoff = (long)blockIdx.z * (long)(gridDim.y * MT) * N;
#pragma unroll
    for (int fm = 0; fm < MF; ++fm)
#pragma unroll
      for (int fn = 0; fn < NF; ++fn) {
        int gm = m0 + wm * (MT / 2) + fm * 16 + quad * 4;
        int gn = n0 + wn * (NT / 2) + fn * 16 + ml;
#pragma unroll
        for (int r = 0; r < 4; ++r)
          Cf[zoff + (long)(gm + r) * N + gn] = acc[fm][fn][r];
      }
  } else {
    ushort_t* C = (ushort_t*)Cv;
#pragma unroll
    for (int fm = 0; fm < MF; ++fm)
#pragma unroll
      for (int fn = 0; fn < NF; ++fn) {
        int gm = m0 + wm * (MT / 2) + fm * 16 + quad * 4;
        int gn = n0 + wn * (NT / 2) + fn * 16 + ml;
#pragma unroll
        for (int r = 0; r < 4; ++r)
          C[(long)(gm + r) * N + gn] = f2bf(acc[fm][fn][r]);
      }
  }
}

// ---------- split-K reduce: out_bf16 = [relu(sum_z p_z + bias[row])] ----------
template<bool RELU_BIAS>
__global__ void reduceZ_kernel(const float* __restrict__ p, ushort_t* __restrict__ out,
                               const float* __restrict__ bias, const int rowShift,
                               const long total4, const long zstride, const int Z) {
  long i = (long)blockIdx.x * blockDim.x + threadIdx.x;
  if (i >= total4) return;
  long e = i * 4;
  float4 s = *(const float4*)(p + e);
  for (int z = 1; z < Z; ++z) {
    float4 b = *(const float4*)(p + (long)z * zstride + e);
    s.x += b.x; s.y += b.y; s.z += b.z; s.w += b.w;
  }
  if constexpr (RELU_BIAS) {
    float bb = bias[e >> rowShift];
    s.x = fmaxf(s.x + bb, 0.f); s.y = fmaxf(s.y + bb, 0.f);
    s.z = fmaxf(s.z + bb, 0.f); s.w = fmaxf(s.w + bb, 0.f);
  }
  uint2 o;
  o.x = pk2(s.x, s.y);
  o.y = pk2(s.z, s.w);
  *(uint2*)(out + e) = o;
}

// ---------- tail: selu(mean) | fc1 | attention | log_softmax (exact fp32) ----------
__global__ void tail_kernel(const float* __restrict__ gacc, const float* __restrict__ sub_fea,
                            const float* __restrict__ fc1_W, const float* __restrict__ fc1_b,
                            const float* __restrict__ att_W, const float* __restrict__ att_a,
                            const float* __restrict__ att_b, float* __restrict__ out) {
  __shared__ float z[768];
  __shared__ float sc[8];
  __shared__ float alpha[8];
  __shared__ float outsh[10];
  const int t = threadIdx.x;  // 256 threads

  for (int j = t; j < 512; j += 256) {
    float x = gacc[j] * (1.0f / 8192.0f);
    const float scale = 1.0507009873554805f, al = 1.6732632423543772f;
    z[j] = x > 0.f ? scale * x : scale * al * (expf(x) - 1.0f);
  }
  {
    float a = fc1_b[t];
    for (int i = 0; i < 128; ++i) a += sub_fea[i] * fc1_W[i * 256 + t];
    z[512 + t] = a;
  }
  if (t < 10) outsh[t] = 0.f;
  __syncthreads();

  {
    int h = t >> 5, ln = t & 31;
    float p = 0.f;
    for (int i = ln; i < 768; i += 32) p += z[i] * att_a[h * 768 + i];
    for (int m = 16; m; m >>= 1) p += __shfl_down(p, m, 32);
    if (ln == 0) sc[h] = p;
  }
  __syncthreads();
  if (t == 0) {
    float mx = sc[0];
    for (int h = 1; h < 8; ++h) mx = fmaxf(mx, sc[h]);
    float s = 0.f, e[8];
    for (int h = 0; h < 8; ++h) { e[h] = expf(sc[h] - mx); s += e[h]; }
    for (int h = 0; h < 8; ++h) alpha[h] = e[h] / s;
  }
  __syncthreads();

  float p[10];
#pragma unroll
  for (int o = 0; o < 10; ++o) p[o] = 0.f;
  for (int i = t; i < 768; i += 256) {
    float zi = z[i];
    for (int h = 0; h < 8; ++h) {
      float za = zi * alpha[h];
      const float* wp = att_W + (h * 768 + i) * 10;
#pragma unroll
      for (int o = 0; o < 10; ++o) p[o] += za * wp[o];
    }
  }
#pragma unroll
  for (int o = 0; o < 10; ++o) atomicAdd(&outsh[o], p[o]);
  __syncthreads();
  if (t == 0) {
    float v[10], mx = -1e30f;
    for (int o = 0; o < 10; ++o) { v[o] = outsh[o] + att_b[o]; mx = fmaxf(mx, v[o]); }
    float s = 0.f;
    for (int o = 0; o < 10; ++o) s += expf(v[o] - mx);
    float lse = logf(s) + mx;
    for (int o = 0; o < 10; ++o) out[o] = v[o] - lse;
  }
}

// ---------- launch ----------
extern "C" void kernel_launch(void* const* d_in, const int* in_sizes, int n_in,
                              void* d_out, int out_size, void* d_ws, size_t ws_size,
                              hipStream_t stream) {
  const float* x       = (const float*)d_in[0];   // [8192,512]
  const float* adj     = (const float*)d_in[1];   // [8192,8192]
  const float* sub_fea = (const float*)d_in[2];   // [1,128]
  const float* gc1_W   = (const float*)d_in[3];   // [512,256]
  const float* gc1_b   = (const float*)d_in[4];   // [256]
  const float* gc2_W   = (const float*)d_in[5];   // [256,512]
  const float* gc2_b   = (const float*)d_in[6];   // [512]
  const float* fc1_W   = (const float*)d_in[7];   // [128,256]
  const float* fc1_b   = (const float*)d_in[8];   // [256]
  const float* att_W   = (const float*)d_in[9];   // [8,768,10]
  const float* att_a   = (const float*)d_in[10];  // [8,768]
  const float* att_b   = (const float*)d_in[11];  // [10]
  float* out = (float*)d_out;

  const size_t MB = 1u << 20;
  // big path: pre-convert adj to bf16 (needs +128 MB of ws)
  const bool big = ws_size >= 224 * MB;

  char* ws = (char*)d_ws;
  size_t off = 0;
  ushort_t* adjbf = (ushort_t*)(ws); if (big) off += 128 * MB;
  ushort_t* xbf   = (ushort_t*)(ws + off); off += 8 * MB;   // [8192,512] bf16
  ushort_t* t1T   = (ushort_t*)(ws + off); off += 4 * MB;   // [256,8192] bf16
  ushort_t* h1T   = (ushort_t*)(ws + off); off += 4 * MB;   // [256,8192] bf16
  ushort_t* P     = (ushort_t*)(ws + off); off += 4 * MB;   // [8192,256] bf16
  float*    part  = (float*)   (ws + off); off += 64 * MB;  // 8 x 2M fp32
  ushort_t* W1T   = (ushort_t*)(ws + off); off += 262144;
  ushort_t* W2T   = (ushort_t*)(ws + off); off += 262144;
  float*    gacc  = (float*)   (ws + off);

  hipMemsetAsync(gacc, 0, 512 * sizeof(float), stream);
  prep_kernel<<<512, 256, 0, stream>>>(gc1_W, gc2_W, W1T, W2T);

  // convert adj (big only) + x to bf16 in one streaming kernel
  if (big) {
    cvt2_kernel<<<32768 + 2048, 256, 0, stream>>>(adj, adjbf, 8388608L, x, xbf, 524288L);
  } else {
    cvt2_kernel<<<2048, 256, 0, stream>>>(x, xbf, 524288L, x, xbf, 0L);
  }

  // L1a: t1T[256,8192] = W1T[256,512] * x^T (BT = xbf), split-K=2
  gemm_bf<128, 128, true, true, 3><<<dim3(64, 2, 2), 256, 0, stream>>>(
      W1T, xbf, nullptr, part, nullptr, 512, 8192);
  reduceZ_kernel<false><<<2048, 256, 0, stream>>>(part, t1T, nullptr, 0, 524288L, 2097152L, 2);

  // L1b: s1T[256,8192] = t1T * adj^T (BT = adj), 256x128 tile, adj read ONCE, split-K=8
  if (big)
    gemm_bf<256, 128, true, true, 3><<<dim3(64, 1, 8), 256, 0, stream>>>(
        t1T, adjbf, nullptr, part, nullptr, 8192, 8192);
  else
    gemm_bf<256, 128, true, false, 3><<<dim3(64, 1, 8), 256, 0, stream>>>(
        t1T, adj, nullptr, part, nullptr, 8192, 8192);
  reduceZ_kernel<true><<<2048, 256, 0, stream>>>(part, h1T, gc1_b, 13, 524288L, 2097152L, 8);

  // L2a: P[8192,256] = adj * h1 (BT = h1T), 128x256 tile, adj read ONCE, split-K=8
  if (big)
    gemm_bf<128, 256, true, true, 3><<<dim3(1, 64, 8), 256, 0, stream>>>(
        adjbf, h1T, nullptr, part, nullptr, 8192, 256);
  else
    gemm_bf<128, 256, false, true, 3><<<dim3(1, 64, 8), 256, 0, stream>>>(
        adj, h1T, nullptr, part, nullptr, 8192, 256);
  reduceZ_kernel<false><<<2048, 256, 0, stream>>>(part, P, nullptr, 0, 524288L, 2097152L, 8);

  // L2b: t2T[512,8192] = W2T * P^T (BT = P); relu(+gc2_b) row-sum -> gacc
  gemm_bf<128, 128, true, true, 2><<<dim3(64, 4, 1), 256, 0, stream>>>(
      W2T, P, gc2_b, nullptr, gacc, 256, 8192);

  tail_kernel<<<1, 256, 0, stream>>>(gacc, sub_fea, fc1_W, fc1_b, att_W, att_a, att_b, out);
}

// Round 4
// 630.537 us; speedup vs baseline: 1.3881x; 1.3881x over previous
//
#include <hip/hip_runtime.h>

typedef __attribute__((ext_vector_type(8))) short short8;
typedef __attribute__((ext_vector_type(4))) float floatx4;
typedef unsigned short ushort_t;
typedef unsigned int u32;

// ---------- helpers ----------
__device__ __forceinline__ ushort_t f2bf(float x) {
  union { float f; unsigned int u; } v; v.f = x;
  unsigned int u = v.u;
  return (ushort_t)((u + 0x7FFFu + ((u >> 16) & 1u)) >> 16);  // RNE
}
__device__ __forceinline__ unsigned int pk2(float a, float b) {
  return (unsigned int)f2bf(a) | ((unsigned int)f2bf(b) << 16);
}
// async global->LDS, 16B per lane (dest = wave-uniform base + lane*16)
__device__ __forceinline__ void gl_lds16(const void* g, void* l) {
  __builtin_amdgcn_global_load_lds(
      (const __attribute__((address_space(1))) u32*)g,
      (__attribute__((address_space(3))) u32*)l, 16, 0, 0);
}

// Tiled layout, RB in {128,256}:  T[rb][kc][r][j],  element (row,k) at
//   ((row/RB)*(K/8) + k/8)*RB*8 + (row%RB)*8 + (k%8)
// One block's K-tile (32 k, RB rows) is RB*64 bytes CONTIGUOUS and identical
// to the LDS quad-major layout -> straight global_load_lds copy.

// ---------- prep: weights -> tiled bf16 (RB=128) ----------
__global__ void prep_t(const float* __restrict__ W1, const float* __restrict__ W2,
                       ushort_t* __restrict__ W1T, ushort_t* __restrict__ W2T) {
  int idx = blockIdx.x * 256 + threadIdx.x;   // 0 .. 131071
  int m = idx >> 9, k = idx & 511;            // W1: m in 256, k in 512
  W1T[((m >> 7) * 64 + (k >> 3)) * 1024 + (m & 127) * 8 + (k & 7)] = f2bf(W1[k * 256 + m]);
  int m2 = idx >> 8, k2 = idx & 255;          // W2: m in 512, k in 256
  W2T[((m2 >> 7) * 32 + (k2 >> 3)) * 1024 + (m2 & 127) * 8 + (k2 & 7)] = f2bf(W2[k2 * 512 + m2]);
}

// ---------- fp32 [R,K] row-major -> tiled bf16 (RB=128), via LDS transpose ----------
// block = 128 rows x 256 k. LDS padded (+1 uint4 per chunk) to spread banks.
__global__ __launch_bounds__(256) void tile_cvt(const float* __restrict__ src,
                                                ushort_t* __restrict__ dst, const int K) {
  __shared__ __align__(16) ushort_t ls[33024];  // 32 chunks * 129 * 8 ushorts
  const int t = threadIdx.x;
  const int rb = blockIdx.y, cb = blockIdx.x;
  const long sbase = (long)rb * 128 * K + cb * 256;
#pragma unroll 4
  for (int i = 0; i < 32; ++i) {
    int flat = i * 256 + t;                 // float4 slot in 128x64
    int row = flat >> 6, kq = flat & 63;    // kq: float4 within row
    float4 v = *(const float4*)(src + sbase + (long)row * K + kq * 4);
    // chunk kc=kq>>1, half=kq&1 ; padded: uint4 slot = kc*129 + row
    *(uint2*)(ls + ((kq >> 1) * 129 + row) * 8 + (kq & 1) * 4) =
        make_uint2(pk2(v.x, v.y), pk2(v.z, v.w));
  }
  __syncthreads();
  ushort_t* ob = dst + ((long)rb * (K >> 3) + cb * 32) * 1024;  // 64KB contiguous
  const uint4* lv = (const uint4*)ls;
  uint4* ov = (uint4*)ob;
#pragma unroll 4
  for (int i = 0; i < 16; ++i) {
    int o = i * 256 + t;                    // out uint4 idx: kc = o>>7, r = o&127
    ov[o] = lv[(o >> 7) * 129 + (o & 127)];
  }
}

// ---------- GEMM on tiled bf16: C[M,N] = A*B^T (both operands row-block tiled) ----------
// MT x NT block tile, 4 waves 2x2, BK=32, m97-style global_load_lds K-loop.
// EPI: 2 = relu(C+bias[m]) row-sum -> atomicAdd gacc[m]; 3 = fp32 partial at z offset.
template<int MT, int NT, int EPI>
__global__ __launch_bounds__(256, 2)
void gemm_t(const ushort_t* __restrict__ A, const ushort_t* __restrict__ B,
            const float* __restrict__ bias, float* __restrict__ Cf,
            float* __restrict__ gacc, const int K, const int N) {
  constexpr int MF = MT / 32, NF = NT / 32;
  constexpr int nA = MT / 64, nB = NT / 64;  // 16B chunks per thread per K-tile
  __shared__ __align__(16) ushort_t Als[MT * 32];
  __shared__ __align__(16) ushort_t Bls[NT * 32];

  const int t = threadIdx.x;
  const int lane = t & 63, w = t >> 6;
  const int wm = w >> 1, wn = w & 1;
  const int ml = lane & 15, quad = lane >> 4;
  const int m0 = blockIdx.y * MT, n0 = blockIdx.x * NT;
  const int Kper = K / gridDim.z, kbeg = blockIdx.z * Kper;

  const char* Ag = (const char*)(A + ((long)((m0 / MT) * (K >> 3) + (kbeg >> 3)) * MT) * 8);
  const char* Bg = (const char*)(B + ((long)((n0 / NT) * (K >> 3) + (kbeg >> 3)) * NT) * 8);

  floatx4 acc[MF][NF] = {};
  const int iters = Kper >> 5;
  for (int it = 0; it < iters; ++it) {
    __syncthreads();                 // prior iter's LDS reads complete
#pragma unroll
    for (int c = 0; c < nA; ++c)
      gl_lds16(Ag + c * 4096 + t * 16, (char*)Als + c * 4096 + t * 16);
#pragma unroll
    for (int c = 0; c < nB; ++c)
      gl_lds16(Bg + c * 4096 + t * 16, (char*)Bls + c * 4096 + t * 16);
    Ag += MT * 64; Bg += NT * 64;
    __syncthreads();                 // drains vmcnt -> LDS tile ready

    short8 av[MF], bv[NF];
#pragma unroll
    for (int f = 0; f < MF; ++f)
      av[f] = *(const short8*)(Als + (quad * MT + wm * (MT / 2) + f * 16 + ml) * 8);
#pragma unroll
    for (int f = 0; f < NF; ++f)
      bv[f] = *(const short8*)(Bls + (quad * NT + wn * (NT / 2) + f * 16 + ml) * 8);
#pragma unroll
    for (int fm = 0; fm < MF; ++fm)
#pragma unroll
      for (int fn = 0; fn < NF; ++fn)
        acc[fm][fn] = __builtin_amdgcn_mfma_f32_16x16x32_bf16(av[fm], bv[fn], acc[fm][fn], 0, 0, 0);
  }

  if constexpr (EPI == 2) {
#pragma unroll
    for (int fm = 0; fm < MF; ++fm) {
      int rowb = m0 + wm * (MT / 2) + fm * 16 + quad * 4;
#pragma unroll
      for (int r = 0; r < 4; ++r) {
        float bb = bias[rowb + r];
        float s = 0.f;
#pragma unroll
        for (int fn = 0; fn < NF; ++fn)
          s += fmaxf(acc[fm][fn][r] + bb, 0.f);
        s += __shfl_xor(s, 1);
        s += __shfl_xor(s, 2);
        s += __shfl_xor(s, 4);
        s += __shfl_xor(s, 8);
        if (ml == 0) atomicAdd(gacc + rowb + r, s);
      }
    }
  } else {
    const long zoff = (long)blockIdx.z * (long)gridDim.y * MT * N;
#pragma unroll
    for (int fm = 0; fm < MF; ++fm)
#pragma unroll
      for (int fn = 0; fn < NF; ++fn) {
        int gm = m0 + wm * (MT / 2) + fm * 16 + quad * 4;
        int gn = n0 + wn * (NT / 2) + fn * 16 + ml;
#pragma unroll
        for (int r = 0; r < 4; ++r)
          Cf[zoff + (long)(gm + r) * N + gn] = acc[fm][fn][r];
      }
  }
}

// ---------- split-K reduce -> tiled bf16 ----------
// MAP 0: logical [256, 8192] -> RB=256 tiled:  o = (k>>3)*2048 + row*8 + (k&7)
// MAP 1: logical [8192, 256] -> RB=128 tiled:  o = (row>>7)*32768 + (k>>3)*1024 + (row&127)*8 + (k&7)
template<bool RELU_BIAS, int MAP>
__global__ void reduceZ(const float* __restrict__ p, ushort_t* __restrict__ outp,
                        const float* __restrict__ bias, const long total4,
                        const long zstride, const int Z) {
  long i = (long)blockIdx.x * blockDim.x + threadIdx.x;
  if (i >= total4) return;
  long e = i * 4;
  float4 s = *(const float4*)(p + e);
  for (int z = 1; z < Z; ++z) {
    float4 b = *(const float4*)(p + (long)z * zstride + e);
    s.x += b.x; s.y += b.y; s.z += b.z; s.w += b.w;
  }
  int row, k;
  if constexpr (MAP == 0) { row = (int)(e >> 13); k = (int)(e & 8191); }
  else                    { row = (int)(e >> 8);  k = (int)(e & 255);  }
  if constexpr (RELU_BIAS) {
    float bb = bias[row];
    s.x = fmaxf(s.x + bb, 0.f); s.y = fmaxf(s.y + bb, 0.f);
    s.z = fmaxf(s.z + bb, 0.f); s.w = fmaxf(s.w + bb, 0.f);
  }
  long o;
  if constexpr (MAP == 0) o = (long)(k >> 3) * 2048 + row * 8 + (k & 7);
  else                    o = (long)(row >> 7) * 32768 + (long)(k >> 3) * 1024 + (row & 127) * 8 + (k & 7);
  *(uint2*)(outp + o) = make_uint2(pk2(s.x, s.y), pk2(s.z, s.w));
}

// ---------- tail: selu(mean) | fc1 | attention | log_softmax (exact fp32) ----------
__global__ void tail_kernel(const float* __restrict__ gacc, const float* __restrict__ sub_fea,
                            const float* __restrict__ fc1_W, const float* __restrict__ fc1_b,
                            const float* __restrict__ att_W, const float* __restrict__ att_a,
                            const float* __restrict__ att_b, float* __restrict__ out) {
  __shared__ float z[768];
  __shared__ float sc[8];
  __shared__ float alpha[8];
  __shared__ float outsh[10];
  const int t = threadIdx.x;  // 256 threads

  for (int j = t; j < 512; j += 256) {
    float x = gacc[j] * (1.0f / 8192.0f);
    const float scale = 1.0507009873554805f, al = 1.6732632423543772f;
    z[j] = x > 0.f ? scale * x : scale * al * (expf(x) - 1.0f);
  }
  {
    float a = fc1_b[t];
    for (int i = 0; i < 128; ++i) a += sub_fea[i] * fc1_W[i * 256 + t];
    z[512 + t] = a;
  }
  if (t < 10) outsh[t] = 0.f;
  __syncthreads();

  {
    int h = t >> 5, ln = t & 31;
    float p = 0.f;
    for (int i = ln; i < 768; i += 32) p += z[i] * att_a[h * 768 + i];
    for (int m = 16; m; m >>= 1) p += __shfl_down(p, m, 32);
    if (ln == 0) sc[h] = p;
  }
  __syncthreads();
  if (t == 0) {
    float mx = sc[0];
    for (int h = 1; h < 8; ++h) mx = fmaxf(mx, sc[h]);
    float s = 0.f, e[8];
    for (int h = 0; h < 8; ++h) { e[h] = expf(sc[h] - mx); s += e[h]; }
    for (int h = 0; h < 8; ++h) alpha[h] = e[h] / s;
  }
  __syncthreads();

  float p[10];
#pragma unroll
  for (int o = 0; o < 10; ++o) p[o] = 0.f;
  for (int i = t; i < 768; i += 256) {
    float zi = z[i];
    for (int h = 0; h < 8; ++h) {
      float za = zi * alpha[h];
      const float* wp = att_W + (h * 768 + i) * 10;
#pragma unroll
      for (int o = 0; o < 10; ++o) p[o] += za * wp[o];
    }
  }
#pragma unroll
  for (int o = 0; o < 10; ++o) atomicAdd(&outsh[o], p[o]);
  __syncthreads();
  if (t == 0) {
    float v[10], mx = -1e30f;
    for (int o = 0; o < 10; ++o) { v[o] = outsh[o] + att_b[o]; mx = fmaxf(mx, v[o]); }
    float s = 0.f;
    for (int o = 0; o < 10; ++o) s += expf(v[o] - mx);
    float lse = logf(s) + mx;
    for (int o = 0; o < 10; ++o) out[o] = v[o] - lse;
  }
}

// ---------- launch ----------
extern "C" void kernel_launch(void* const* d_in, const int* in_sizes, int n_in,
                              void* d_out, int out_size, void* d_ws, size_t ws_size,
                              hipStream_t stream) {
  const float* x       = (const float*)d_in[0];   // [8192,512]
  const float* adj     = (const float*)d_in[1];   // [8192,8192]
  const float* sub_fea = (const float*)d_in[2];   // [1,128]
  const float* gc1_W   = (const float*)d_in[3];   // [512,256]
  const float* gc1_b   = (const float*)d_in[4];   // [256]
  const float* gc2_W   = (const float*)d_in[5];   // [256,512]
  const float* gc2_b   = (const float*)d_in[6];   // [512]
  const float* fc1_W   = (const float*)d_in[7];   // [128,256]
  const float* fc1_b   = (const float*)d_in[8];   // [256]
  const float* att_W   = (const float*)d_in[9];   // [8,768,10]
  const float* att_a   = (const float*)d_in[10];  // [8,768]
  const float* att_b   = (const float*)d_in[11];  // [10]
  float* out = (float*)d_out;

  const size_t MB = 1u << 20;
  char* ws = (char*)d_ws;
  size_t off = 0;
  ushort_t* adjT = (ushort_t*)(ws + off); off += 128 * MB;  // tiled bf16 adj
  ushort_t* xT   = (ushort_t*)(ws + off); off += 8 * MB;    // tiled bf16 x
  ushort_t* t1T  = (ushort_t*)(ws + off); off += 4 * MB;    // [256,8192] tiled RB=256
  ushort_t* h1T  = (ushort_t*)(ws + off); off += 4 * MB;    // [256,8192] tiled RB=256
  ushort_t* P_t  = (ushort_t*)(ws + off); off += 4 * MB;    // [8192,256] tiled RB=128
  float*    part = (float*)   (ws + off); off += 64 * MB;   // 8 x 2M fp32 partials
  ushort_t* W1T  = (ushort_t*)(ws + off); off += 262144;
  ushort_t* W2T  = (ushort_t*)(ws + off); off += 262144;
  float*    gacc = (float*)   (ws + off);

  hipMemsetAsync(gacc, 0, 512 * sizeof(float), stream);
  prep_t<<<512, 256, 0, stream>>>(gc1_W, gc2_W, W1T, W2T);

  // tiled bf16 conversions (adj serves both L1b-B and L2a-A)
  tile_cvt<<<dim3(32, 64), 256, 0, stream>>>(adj, adjT, 8192);
  tile_cvt<<<dim3(2, 64), 256, 0, stream>>>(x, xT, 512);

  // L1a: t1T[256,8192] = W1T * x^T, split-K=2
  gemm_t<128, 128, 3><<<dim3(64, 2, 2), 256, 0, stream>>>(W1T, xT, nullptr, part, nullptr, 512, 8192);
  reduceZ<false, 0><<<2048, 256, 0, stream>>>(part, t1T, nullptr, 524288L, 2097152L, 2);

  // L1b: s1T[256,8192] = t1T * adj^T, 256x128 tile, adj read once, split-K=8
  gemm_t<256, 128, 3><<<dim3(64, 1, 8), 256, 0, stream>>>(t1T, adjT, nullptr, part, nullptr, 8192, 8192);
  reduceZ<true, 0><<<2048, 256, 0, stream>>>(part, h1T, gc1_b, 524288L, 2097152L, 8);

  // L2a: P[8192,256] = adj * h1, 128x256 tile, adj read once, split-K=8
  gemm_t<128, 256, 3><<<dim3(1, 64, 8), 256, 0, stream>>>(adjT, h1T, nullptr, part, nullptr, 8192, 256);
  reduceZ<false, 1><<<2048, 256, 0, stream>>>(part, P_t, nullptr, 524288L, 2097152L, 8);

  // L2b: t2T[512,8192] = W2T * P^T ; relu(+gc2_b) row-sum -> gacc
  gemm_t<128, 128, 2><<<dim3(64, 4, 1), 256, 0, stream>>>(W2T, P_t, gc2_b, nullptr, gacc, 256, 8192);

  tail_kernel<<<1, 256, 0, stream>>>(gacc, sub_fea, fc1_W, fc1_b, att_W, att_a, att_b, out);
}